// Round 6
// baseline (75800.922 us; speedup 1.0000x reference)
//
#include <hip/hip_runtime.h>

// VQ forward on MI355X — round 6: single-product bf16 MFMA screen (32x32x16)
// + exact fp32 rescore. x: [32768,512] fp32, codebook: [8192,512] fp32.
// d_out (fp32): [16.7M) quantized_st | [1] vq_loss | [32768] idx-as-float
//
// R5 post-mortem (1638us, MfmaUtil 28.6%): (a) 3 split-products were overkill —
// codebook is uniform(+-1/8192), so single bf16xbf16 dot error ~8e-6 << MARGIN
// 2.5e-4 (30 sigma); (b) 16x16x32 needs 0.125 B/FLOP from LDS = 4x over the
// ~100 B/cyc LDS pipe -> ~25% cap (measured 28.6%); 32x32x16 with 4x4 frag
// tile = 0.023 B/FLOP; (c) per-round fp32->bf16 convert burned VALU. R6:
// pre-convert x & cb to bf16 in d_out scratch; coarse = 256thr/block, wave
// tile 128x128 (acc 256 regs, 1 wave/SIMD), block = 128 rows x all codes,
// BK=32, register-prefetch pipeline, XOR-swizzled LDS (bank-uniform b128).
// Screen: prefix-min + margin append (same as R5, which passed absmax 0);
// rescore does R1's bit-exact fp32 chain on ~4 candidates/row.

#define NROWS 32768
#define KCODES 8192
#define DD 512
#define CAP 24
#define MARGIN 2.5e-4f

typedef __bf16 bf16_t;
typedef __bf16 bf16x4 __attribute__((ext_vector_type(4)));
typedef __bf16 bf16x8 __attribute__((ext_vector_type(8)));
typedef float f32x16 __attribute__((ext_vector_type(16)));

// LDS layout for a [rows][32k] bf16 tile: 16B chunk (row, slot s in 0..3) at
// row*32 + ((s ^ ((row>>1)&3))<<3) bf16. Frag reads (32 consecutive rows,
// slot = ks*2+h) and staged writes both hit every bank exactly 8x per wave
// (the b128 floor) -> conflict-free.
__device__ __forceinline__ int lofs(int row, int s) {
  return row * 32 + (((s ^ ((row >> 1) & 3))) << 3);
}

// ---------------- sum of fp32 squares per row (fp64 accumulate, round to fp32)
__global__ __launch_bounds__(256) void sumsq_kernel(const float* __restrict__ in,
                                                    float* __restrict__ out,
                                                    int nrows) {
  const int wave = threadIdx.x >> 6;
  const int lane = threadIdx.x & 63;
  const int row = blockIdx.x * 4 + wave;
  if (row >= nrows) return;
  const float* p = in + (size_t)row * DD;
  double s = 0.0;
#pragma unroll
  for (int j = 0; j < DD / 64; ++j) {
    float v = p[j * 64 + lane];
    float sq = v * v;
    s += (double)sq;
  }
  for (int off = 32; off > 0; off >>= 1) s += __shfl_down(s, off, 64);
  if (lane == 0) out[row] = (float)s;
}

// ---------------- fp32 -> bf16 (RNE) bulk convert
__global__ __launch_bounds__(256) void cvt_kernel(const float* __restrict__ in,
                                                  bf16_t* __restrict__ outb) {
  const int t = blockIdx.x * 256 + threadIdx.x;
  float4 v = *(const float4*)(in + (size_t)t * 4);
  bf16x4 o = {(bf16_t)v.x, (bf16_t)v.y, (bf16_t)v.z, (bf16_t)v.w};
  *(bf16x4*)(outb + (size_t)t * 4) = o;
}

// ---------------- coarse: bf16 MFMA GEMM + prefix-min margin screen
__global__ __launch_bounds__(256) void coarse_kernel(
    const bf16_t* __restrict__ xbf, const bf16_t* __restrict__ cbbf,
    const float* __restrict__ csq, int* __restrict__ cnt_g,
    int* __restrict__ list_g) {
  __shared__ bf16_t As[128 * 32];               //  8 KB
  __shared__ bf16_t Bs[512 * 32];               // 32 KB
  __shared__ unsigned long long best[128];      // packed (dist_bits<<32)|code
  __shared__ int cnt_l[128];
  __shared__ int list_l[128 * CAP];

  const int tid = threadIdx.x;
  const int w = tid >> 6;
  const int lane = tid & 63;
  const int l31 = lane & 31;
  const int h = lane >> 5;
  const int row0 = blockIdx.x * 128;

  for (int i = tid; i < 128; i += 256) { best[i] = ~0ULL; cnt_l[i] = 0; }

  // staging assignments (constant all kernel)
  const int ar = tid & 127;                 // A row
  const int as0 = (tid >> 7) * 2;           // A slots as0, as0+1
  const int aofs0 = lofs(ar, as0);
  const int aofs1 = lofs(ar, as0 + 1);
  const bf16_t* xrow = xbf + (size_t)(row0 + ar) * DD + as0 * 8;

  int bcode[4], bofs[4];
  const bf16_t* cbp[4];
#pragma unroll
  for (int j = 0; j < 4; ++j) {
    const int flat = j * 256 + tid;
    bcode[j] = flat >> 2;
    const int bs = flat & 3;
    bofs[j] = lofs(bcode[j], bs);
    cbp[j] = cbbf + (size_t)bcode[j] * DD + bs * 8;
  }

  // fragment read offsets (constant)
  int afofs[4][2], bfofs[4][2];
#pragma unroll
  for (int rt = 0; rt < 4; ++rt) {
    const int arow = rt * 32 + l31;
#pragma unroll
    for (int ks = 0; ks < 2; ++ks) afofs[rt][ks] = lofs(arow, ks * 2 + h);
  }
#pragma unroll
  for (int ct = 0; ct < 4; ++ct) {
    const int brow = w * 128 + ct * 32 + l31;
#pragma unroll
    for (int ks = 0; ks < 2; ++ks) bfofs[ct][ks] = lofs(brow, ks * 2 + h);
  }

  // prime prefetch for (ci=0, kc=0)
  bf16x8 pa0 = *(const bf16x8*)(xrow);
  bf16x8 pa1 = *(const bf16x8*)(xrow + 8);
  bf16x8 pb[4];
#pragma unroll
  for (int j = 0; j < 4; ++j) pb[j] = *(const bf16x8*)(cbp[j]);

  __syncthreads();   // best/cnt init visible

#pragma unroll 1
  for (int ci = 0; ci < KCODES / 512; ++ci) {
    const int c0 = ci * 512;
    f32x16 acc[4][4];
#pragma unroll
    for (int rt = 0; rt < 4; ++rt)
#pragma unroll
      for (int ct = 0; ct < 4; ++ct)
#pragma unroll
        for (int e = 0; e < 16; ++e) acc[rt][ct][e] = 0.0f;

#pragma unroll 1
    for (int kc = 0; kc < DD / 32; ++kc) {
      // store prefetched round to LDS
      *(bf16x8*)&As[aofs0] = pa0;
      *(bf16x8*)&As[aofs1] = pa1;
#pragma unroll
      for (int j = 0; j < 4; ++j) *(bf16x8*)&Bs[bofs[j]] = pb[j];
      __syncthreads();

      // prefetch next round (next kc, or next ci's kc=0)
      {
        int nci = ci, nkc = kc + 1;
        if (nkc == DD / 32) { nkc = 0; ++nci; }
        if (nci < KCODES / 512) {
          const int nkb = nkc * 32;
          const size_t ncoff = (size_t)(nci * 512) * DD + nkb;
          pa0 = *(const bf16x8*)(xrow + nkb);
          pa1 = *(const bf16x8*)(xrow + nkb + 8);
#pragma unroll
          for (int j = 0; j < 4; ++j) pb[j] = *(const bf16x8*)(cbp[j] + ncoff);
        }
      }

      // MFMA: 2 k-steps of 16, 4x4 tile of 32x32
#pragma unroll
      for (int ks = 0; ks < 2; ++ks) {
        bf16x8 af[4], bfr[4];
#pragma unroll
        for (int rt = 0; rt < 4; ++rt) af[rt] = *(const bf16x8*)&As[afofs[rt][ks]];
#pragma unroll
        for (int ct = 0; ct < 4; ++ct) bfr[ct] = *(const bf16x8*)&Bs[bfofs[ct][ks]];
#pragma unroll
        for (int rt = 0; rt < 4; ++rt)
#pragma unroll
          for (int ct = 0; ct < 4; ++ct)
            acc[rt][ct] = __builtin_amdgcn_mfma_f32_32x32x16_bf16(
                af[rt], bfr[ct], acc[rt][ct], 0, 0, 0);
      }
      __syncthreads();
    }

    // ---- screen this 512-code tile. d' = 1 + csq - 2*dot (>0, bit-orderable)
    float cs1[4];
#pragma unroll
    for (int ct = 0; ct < 4; ++ct)
      cs1[ct] = 1.0f + csq[c0 + w * 128 + ct * 32 + l31];

    // running min -> best[] (C/D layout m74/m101: col=lane&31,
    // row=(reg&3)+8*(reg>>2)+4*(lane>>5))
#pragma unroll
    for (int rt = 0; rt < 4; ++rt) {
#pragma unroll
      for (int reg = 0; reg < 16; ++reg) {
        unsigned long long pk = ~0ULL;
#pragma unroll
        for (int ct = 0; ct < 4; ++ct) {
          float d = fmaf(-2.0f, acc[rt][ct][reg], cs1[ct]);
          unsigned long long p =
              ((unsigned long long)__float_as_uint(d) << 32) |
              (unsigned)(c0 + w * 128 + ct * 32 + l31);
          if (p < pk) pk = p;
        }
#pragma unroll
        for (int m = 1; m <= 16; m <<= 1) {
          unsigned long long o = __shfl_xor(pk, m, 64);
          if (o < pk) pk = o;
        }
        if (l31 == 0) {
          const int row = rt * 32 + (reg & 3) + 8 * (reg >> 2) + 4 * h;
          atomicMin(&best[row], pk);
        }
      }
    }
    __syncthreads();

    // append pass vs prefix-min threshold
#pragma unroll
    for (int rt = 0; rt < 4; ++rt) {
#pragma unroll
      for (int reg = 0; reg < 16; ++reg) {
        const int row = rt * 32 + (reg & 3) + 8 * (reg >> 2) + 4 * h;
        const float thr = __uint_as_float((unsigned)(best[row] >> 32)) + MARGIN;
#pragma unroll
        for (int ct = 0; ct < 4; ++ct) {
          float d = fmaf(-2.0f, acc[rt][ct][reg], cs1[ct]);
          if (d <= thr) {
            int pos = atomicAdd(&cnt_l[row], 1);
            if (pos < CAP)
              list_l[row * CAP + pos] = c0 + w * 128 + ct * 32 + l31;
          }
        }
      }
    }
    __syncthreads();
  }

  for (int i = tid; i < 128; i += 256) cnt_g[row0 + i] = cnt_l[i];
  for (int i = tid; i < 128 * CAP; i += 256)
    list_g[(size_t)row0 * CAP + i] = list_l[i];
}

// ---------------- phase 2: exact rescore of candidates (R1's bit-exact chain)
__global__ __launch_bounds__(256) void rescore_kernel(
    const float* __restrict__ x, const float* __restrict__ cb,
    const float* __restrict__ xsq, const float* __restrict__ csq,
    const int* __restrict__ list, const int* __restrict__ cnt,
    int* __restrict__ idxbuf) {
  const int row = blockIdx.x * 4 + (threadIdx.x >> 6);
  const int lane = threadIdx.x & 63;
  const int n = cnt[row];
  const float xs = xsq[row];
  const float4* xr4 = (const float4*)(x + (size_t)row * DD);
  unsigned long long bestv = ~0ULL;

  if (n >= 1 && n <= CAP) {
    if (lane < n) {
      const int idx = list[(size_t)row * CAP + lane];
      const float4* cr4 = (const float4*)(cb + (size_t)idx * DD);
      float acc = 0.0f;
      for (int k4 = 0; k4 < DD / 4; ++k4) {     // sequential ascending k: R1 order
        float4 xv = xr4[k4];
        float4 cv = cr4[k4];
        acc = fmaf(xv.x, cv.x, acc);
        acc = fmaf(xv.y, cv.y, acc);
        acc = fmaf(xv.z, cv.z, acc);
        acc = fmaf(xv.w, cv.w, acc);
      }
      float t = xs - 2.0f * acc;
      float d = t + csq[idx];
      bestv = ((unsigned long long)__float_as_uint(d) << 32) | (unsigned)idx;
    }
  } else {
    // safety fallback: full exact scan
    for (int idx = lane; idx < KCODES; idx += 64) {
      const float4* cr4 = (const float4*)(cb + (size_t)idx * DD);
      float acc = 0.0f;
      for (int k4 = 0; k4 < DD / 4; ++k4) {
        float4 xv = xr4[k4];
        float4 cv = cr4[k4];
        acc = fmaf(xv.x, cv.x, acc);
        acc = fmaf(xv.y, cv.y, acc);
        acc = fmaf(xv.z, cv.z, acc);
        acc = fmaf(xv.w, cv.w, acc);
      }
      float t = xs - 2.0f * acc;
      float d = t + csq[idx];
      unsigned long long pk =
          ((unsigned long long)__float_as_uint(d) << 32) | (unsigned)idx;
      if (pk < bestv) bestv = pk;
    }
  }
#pragma unroll
  for (int s = 1; s <= 32; s <<= 1) {
    unsigned long long o = __shfl_xor(bestv, s, 64);
    if (o < bestv) bestv = o;
  }
  if (lane == 0) idxbuf[row] = (int)(bestv & 0xffffffffu);
}

// ---------------- gather + straight-through + loss partial + idx-as-float
__global__ __launch_bounds__(128) void epilogue_kernel(
    const float* __restrict__ x, const float* __restrict__ cb,
    const int* __restrict__ idxbuf, float* __restrict__ out_q,
    float* __restrict__ out_idx_f, double* __restrict__ partials) {
  const int row = blockIdx.x;
  const int t = threadIdx.x;
  const int k = idxbuf[row];

  const float4* xr = (const float4*)(x + (size_t)row * DD);
  const float4* qr = (const float4*)(cb + (size_t)k * DD);
  float4* orow = (float4*)(out_q + (size_t)row * DD);

  float4 xv = xr[t];
  float4 qv = qr[t];
  float dx = qv.x - xv.x, dy = qv.y - xv.y, dz = qv.z - xv.z, dw = qv.w - xv.w;
  float4 o;
  o.x = xv.x + dx; o.y = xv.y + dy; o.z = xv.z + dz; o.w = xv.w + dw;
  orow[t] = o;

  float s0 = dx * dx, s1 = dy * dy, s2 = dz * dz, s3 = dw * dw;
  double part = (double)s0 + (double)s1 + (double)s2 + (double)s3;
  for (int off = 32; off > 0; off >>= 1) part += __shfl_down(part, off, 64);
  __shared__ double red[2];
  const int lane = t & 63, wv = t >> 6;
  if (lane == 0) red[wv] = part;
  __syncthreads();
  if (t == 0) {
    partials[row] = red[0] + red[1];
    out_idx_f[row] = (float)k;
  }
}

// ---------------- reduce partials -> vq_loss
__global__ __launch_bounds__(256) void finalize_kernel(
    const double* __restrict__ partials, float* __restrict__ out_loss) {
  __shared__ double red[256];
  double s = 0.0;
  for (int i = threadIdx.x; i < NROWS; i += 256) s += partials[i];
  red[threadIdx.x] = s;
  __syncthreads();
  for (int st = 128; st > 0; st >>= 1) {
    if (threadIdx.x < st) red[threadIdx.x] += red[threadIdx.x + st];
    __syncthreads();
  }
  if (threadIdx.x == 0) {
    double mean = red[0] / ((double)NROWS * (double)DD);
    float cl = (float)mean;
    out_loss[0] = cl + 0.25f * cl;
  }
}

extern "C" void kernel_launch(void* const* d_in, const int* in_sizes, int n_in,
                              void* d_out, int out_size, void* d_ws,
                              size_t ws_size, hipStream_t stream) {
  const float* x = (const float*)d_in[0];
  const float* cb = (const float*)d_in[1];
  float* out = (float*)d_out;

  // ws: partials | idxbuf | csq | xsq | cnt | list  (~4.5 MB)
  char* ws = (char*)d_ws;
  double* partials = (double*)ws;                          // 262144 B
  int* idxbuf = (int*)(ws + 262144);                       // 131072 B
  float* csq = (float*)(ws + 262144 + 131072);             //  32768 B
  float* xsq = (float*)(ws + 262144 + 131072 + 32768);     // 131072 B
  int* cnt = (int*)(ws + 262144 + 131072 + 32768 + 131072);           // 131072 B
  int* list = (int*)(ws + 262144 + 131072 + 32768 + 131072 + 131072); // 3.1 MB

  // bf16 copies live in d_out scratch (overwritten by epilogue later):
  // cbbf 8 MB, xbf 32 MB -> 40 MB of the 67 MB output buffer.
  bf16_t* cbbf = (bf16_t*)d_out;
  bf16_t* xbf = cbbf + (size_t)KCODES * DD;

  sumsq_kernel<<<KCODES / 4, 256, 0, stream>>>(cb, csq, KCODES);
  sumsq_kernel<<<NROWS / 4, 256, 0, stream>>>(x, xsq, NROWS);
  cvt_kernel<<<(KCODES * DD / 4) / 256, 256, 0, stream>>>(cb, cbbf);
  cvt_kernel<<<(NROWS * DD / 4) / 256, 256, 0, stream>>>(x, xbf);
  coarse_kernel<<<NROWS / 128, 256, 0, stream>>>(xbf, cbbf, csq, cnt, list);
  rescore_kernel<<<NROWS / 4, 256, 0, stream>>>(x, cb, xsq, csq, list, cnt, idxbuf);
  epilogue_kernel<<<NROWS, 128, 0, stream>>>(x, cb, idxbuf, out,
                                             out + 16777216 + 1, partials);
  finalize_kernel<<<1, 256, 0, stream>>>(partials, out + 16777216);
}

// Round 7
// 2587.022 us; speedup vs baseline: 29.3005x; 29.3005x over previous
//
#include <hip/hip_runtime.h>

// VQ forward on MI355X — round 7: fully-staged 16x16x32 bf16 MFMA screen
// + exact fp32 rescore. x: [32768,512] fp32, codebook: [8192,512] fp32.
// d_out (fp32): [16.7M) quantized_st | [1] vq_loss | [32768] idx-as-float
//
// R6 post-mortem: B staging only covered codes 0..255 of each 512-code tile
// (flat>>2 with j<4). Waves 2/3 ran MFMA on stale LDS -> fake dots overflowed
// to +-Inf -> d=-Inf tie-cascade appended thousands of candidates per row ->
// cnt>CAP everywhere -> rescore took the exact full-scan fallback for ALL rows
// (73 ms, absmax 0). R7: (a) stage all 2048 B chunks (j<8, pb[8]); (b) use
// 16x16x32 MFMA whose A/B/C-D layouts are HW-verified (R5 candidate path
// passed end-to-end; m89/m91), instead of the never-validated 32x32 layouts.
// Wave tile stays 128x128 (8x8 grid of 16x16), acc=256 regs, 1 wave/SIMD,
// (256,1) for the 512-VGPR budget. With full staging, kernel behavior is
// independent of initial LDS contents.

#define NROWS 32768
#define KCODES 8192
#define DD 512
#define CAP 24
#define MARGIN 2.5e-4f

typedef __bf16 bf16_t;
typedef __bf16 bf16x4 __attribute__((ext_vector_type(4)));
typedef __bf16 bf16x8 __attribute__((ext_vector_type(8)));
typedef float f32x4 __attribute__((ext_vector_type(4)));

// LDS layout for a [rows][32k] bf16 tile: 16B chunk (row, slot s in 0..3) at
// row*32 + ((s ^ ((row>>1)&3))<<3) bf16. Full-row reads/writes hit the 8-phase
// bank floor (conflict-free); the xor spreads fixed-slot accesses.
__device__ __forceinline__ int lofs(int row, int s) {
  return row * 32 + (((s ^ ((row >> 1) & 3))) << 3);
}

// ---------------- sum of fp32 squares per row (fp64 accumulate, round to fp32)
__global__ __launch_bounds__(256) void sumsq_kernel(const float* __restrict__ in,
                                                    float* __restrict__ out,
                                                    int nrows) {
  const int wave = threadIdx.x >> 6;
  const int lane = threadIdx.x & 63;
  const int row = blockIdx.x * 4 + wave;
  if (row >= nrows) return;
  const float* p = in + (size_t)row * DD;
  double s = 0.0;
#pragma unroll
  for (int j = 0; j < DD / 64; ++j) {
    float v = p[j * 64 + lane];
    float sq = v * v;
    s += (double)sq;
  }
  for (int off = 32; off > 0; off >>= 1) s += __shfl_down(s, off, 64);
  if (lane == 0) out[row] = (float)s;
}

// ---------------- fp32 -> bf16 (RNE) bulk convert
__global__ __launch_bounds__(256) void cvt_kernel(const float* __restrict__ in,
                                                  bf16_t* __restrict__ outb) {
  const int t = blockIdx.x * 256 + threadIdx.x;
  float4 v = *(const float4*)(in + (size_t)t * 4);
  bf16x4 o = {(bf16_t)v.x, (bf16_t)v.y, (bf16_t)v.z, (bf16_t)v.w};
  *(bf16x4*)(outb + (size_t)t * 4) = o;
}

// ---------------- coarse: bf16 MFMA GEMM (16x16x32) + prefix-min margin screen
__global__ __launch_bounds__(256, 1) void coarse_kernel(
    const bf16_t* __restrict__ xbf, const bf16_t* __restrict__ cbbf,
    const float* __restrict__ csq, int* __restrict__ cnt_g,
    int* __restrict__ list_g) {
  __shared__ bf16_t As[128 * 32];               //  8 KB
  __shared__ bf16_t Bs[512 * 32];               // 32 KB
  __shared__ unsigned long long best[128];      // packed (dist_bits<<32)|code
  __shared__ int cnt_l[128];
  __shared__ int list_l[128 * CAP];             // 12 KB

  const int tid = threadIdx.x;
  const int w = tid >> 6;            // wave: cols w*128..+127
  const int lane = tid & 63;
  const int q = lane >> 4;           // quad: A/B k-group q*8..q*8+7
  const int l15 = lane & 15;
  const int row0 = blockIdx.x * 128;

  for (int i = tid; i < 128; i += 256) { best[i] = ~0ULL; cnt_l[i] = 0; }

  // A staging: thread -> row ar, slots as0, as0+1 (16 contiguous k each round)
  const int ar = tid & 127;
  const int as0 = (tid >> 7) * 2;
  const int aofs0 = lofs(ar, as0);
  const int aofs1 = lofs(ar, as0 + 1);
  const bf16_t* xrow = xbf + (size_t)(row0 + ar) * DD + as0 * 8;

  // B staging: 2048 chunks (512 codes x 4 slots) / 256 thr = 8 per thread
  int bofs[8];
  const bf16_t* cbp[8];
#pragma unroll
  for (int j = 0; j < 8; ++j) {
    const int flat = j * 256 + tid;        // 0..2047
    const int bcode = flat >> 2;           // 0..511  (FULL tile — the R6 fix)
    const int bs = flat & 3;
    bofs[j] = lofs(bcode, bs);
    cbp[j] = cbbf + (size_t)bcode * DD + bs * 8;
  }

  // fragment read offsets: A rows rt*16+l15 slot q; B rows w*128+ct*16+l15 slot q
  int afofs[8], bfofs[8];
#pragma unroll
  for (int rt = 0; rt < 8; ++rt) afofs[rt] = lofs(rt * 16 + l15, q);
#pragma unroll
  for (int ct = 0; ct < 8; ++ct) bfofs[ct] = lofs(w * 128 + ct * 16 + l15, q);

  // prime prefetch for (ci=0, kc=0)
  bf16x8 pa0 = *(const bf16x8*)(xrow);
  bf16x8 pa1 = *(const bf16x8*)(xrow + 8);
  bf16x8 pb[8];
#pragma unroll
  for (int j = 0; j < 8; ++j) pb[j] = *(const bf16x8*)(cbp[j]);

  __syncthreads();   // best/cnt init visible

#pragma unroll 1
  for (int ci = 0; ci < KCODES / 512; ++ci) {
    const int c0 = ci * 512;
    f32x4 acc[8][8];
#pragma unroll
    for (int rt = 0; rt < 8; ++rt)
#pragma unroll
      for (int ct = 0; ct < 8; ++ct) {
        f32x4 z = {0.f, 0.f, 0.f, 0.f};
        acc[rt][ct] = z;
      }

#pragma unroll 1
    for (int kc = 0; kc < DD / 32; ++kc) {
      // store prefetched round to LDS
      *(bf16x8*)&As[aofs0] = pa0;
      *(bf16x8*)&As[aofs1] = pa1;
#pragma unroll
      for (int j = 0; j < 8; ++j) *(bf16x8*)&Bs[bofs[j]] = pb[j];
      __syncthreads();

      // prefetch next round (next kc, or next ci's kc=0)
      {
        int nci = ci, nkc = kc + 1;
        if (nkc == DD / 32) { nkc = 0; ++nci; }
        if (nci < KCODES / 512) {
          const int nkb = nkc * 32;
          const size_t ncoff = (size_t)(nci * 512) * DD + nkb;
          pa0 = *(const bf16x8*)(xrow + nkb);
          pa1 = *(const bf16x8*)(xrow + nkb + 8);
#pragma unroll
          for (int j = 0; j < 8; ++j) pb[j] = *(const bf16x8*)(cbp[j] + ncoff);
        }
      }

      // fragments + 64 MFMAs (16x16x32: one K=32 step per kc round)
      bf16x8 af[8], bfr[8];
#pragma unroll
      for (int rt = 0; rt < 8; ++rt) af[rt] = *(const bf16x8*)&As[afofs[rt]];
#pragma unroll
      for (int ct = 0; ct < 8; ++ct) bfr[ct] = *(const bf16x8*)&Bs[bfofs[ct]];
#pragma unroll
      for (int rt = 0; rt < 8; ++rt)
#pragma unroll
        for (int ct = 0; ct < 8; ++ct)
          acc[rt][ct] = __builtin_amdgcn_mfma_f32_16x16x32_bf16(
              af[rt], bfr[ct], acc[rt][ct], 0, 0, 0);
      __syncthreads();
    }

    // ---- screen this 512-code tile. d' = 1 + csq - 2*dot (>0, bit-orderable)
    float cs1[8];
#pragma unroll
    for (int ct = 0; ct < 8; ++ct)
      cs1[ct] = 1.0f + csq[c0 + w * 128 + ct * 16 + l15];

    // min pass (C/D layout m89: col=lane&15, row=q*4+reg)
#pragma unroll
    for (int rt = 0; rt < 8; ++rt) {
#pragma unroll
      for (int reg = 0; reg < 4; ++reg) {
        unsigned long long pk = ~0ULL;
#pragma unroll
        for (int ct = 0; ct < 8; ++ct) {
          float d = fmaf(-2.0f, acc[rt][ct][reg], cs1[ct]);
          unsigned long long p =
              ((unsigned long long)__float_as_uint(d) << 32) |
              (unsigned)(c0 + w * 128 + ct * 16 + l15);
          if (p < pk) pk = p;
        }
#pragma unroll
        for (int m = 1; m <= 8; m <<= 1) {
          unsigned long long o = __shfl_xor(pk, m, 64);
          if (o < pk) pk = o;
        }
        if (l15 == 0) atomicMin(&best[rt * 16 + q * 4 + reg], pk);
      }
    }
    __syncthreads();

    // append pass vs prefix-min threshold
#pragma unroll
    for (int rt = 0; rt < 8; ++rt) {
#pragma unroll
      for (int reg = 0; reg < 4; ++reg) {
        const int rloc = rt * 16 + q * 4 + reg;
        const float thr = __uint_as_float((unsigned)(best[rloc] >> 32)) + MARGIN;
#pragma unroll
        for (int ct = 0; ct < 8; ++ct) {
          float d = fmaf(-2.0f, acc[rt][ct][reg], cs1[ct]);
          if (d <= thr) {
            int pos = atomicAdd(&cnt_l[rloc], 1);
            if (pos < CAP)
              list_l[rloc * CAP + pos] = c0 + w * 128 + ct * 16 + l15;
          }
        }
      }
    }
    __syncthreads();
  }

  for (int i = tid; i < 128; i += 256) cnt_g[row0 + i] = cnt_l[i];
  for (int i = tid; i < 128 * CAP; i += 256)
    list_g[(size_t)row0 * CAP + i] = list_l[i];
}

// ---------------- phase 2: exact rescore of candidates (R1's bit-exact chain)
__global__ __launch_bounds__(256) void rescore_kernel(
    const float* __restrict__ x, const float* __restrict__ cb,
    const float* __restrict__ xsq, const float* __restrict__ csq,
    const int* __restrict__ list, const int* __restrict__ cnt,
    int* __restrict__ idxbuf) {
  const int row = blockIdx.x * 4 + (threadIdx.x >> 6);
  const int lane = threadIdx.x & 63;
  const int n = cnt[row];
  const float xs = xsq[row];
  const float4* xr4 = (const float4*)(x + (size_t)row * DD);
  unsigned long long bestv = ~0ULL;

  if (n >= 1 && n <= CAP) {
    if (lane < n) {
      const int idx = list[(size_t)row * CAP + lane];
      const float4* cr4 = (const float4*)(cb + (size_t)idx * DD);
      float acc = 0.0f;
      for (int k4 = 0; k4 < DD / 4; ++k4) {     // sequential ascending k: R1 order
        float4 xv = xr4[k4];
        float4 cv = cr4[k4];
        acc = fmaf(xv.x, cv.x, acc);
        acc = fmaf(xv.y, cv.y, acc);
        acc = fmaf(xv.z, cv.z, acc);
        acc = fmaf(xv.w, cv.w, acc);
      }
      float t = xs - 2.0f * acc;
      float d = t + csq[idx];
      bestv = ((unsigned long long)__float_as_uint(d) << 32) | (unsigned)idx;
    }
  } else {
    // safety fallback: full exact scan
    for (int idx = lane; idx < KCODES; idx += 64) {
      const float4* cr4 = (const float4*)(cb + (size_t)idx * DD);
      float acc = 0.0f;
      for (int k4 = 0; k4 < DD / 4; ++k4) {
        float4 xv = xr4[k4];
        float4 cv = cr4[k4];
        acc = fmaf(xv.x, cv.x, acc);
        acc = fmaf(xv.y, cv.y, acc);
        acc = fmaf(xv.z, cv.z, acc);
        acc = fmaf(xv.w, cv.w, acc);
      }
      float t = xs - 2.0f * acc;
      float d = t + csq[idx];
      unsigned long long pk =
          ((unsigned long long)__float_as_uint(d) << 32) | (unsigned)idx;
      if (pk < bestv) bestv = pk;
    }
  }
#pragma unroll
  for (int s = 1; s <= 32; s <<= 1) {
    unsigned long long o = __shfl_xor(bestv, s, 64);
    if (o < bestv) bestv = o;
  }
  if (lane == 0) idxbuf[row] = (int)(bestv & 0xffffffffu);
}

// ---------------- gather + straight-through + loss partial + idx-as-float
__global__ __launch_bounds__(128) void epilogue_kernel(
    const float* __restrict__ x, const float* __restrict__ cb,
    const int* __restrict__ idxbuf, float* __restrict__ out_q,
    float* __restrict__ out_idx_f, double* __restrict__ partials) {
  const int row = blockIdx.x;
  const int t = threadIdx.x;
  const int k = idxbuf[row];

  const float4* xr = (const float4*)(x + (size_t)row * DD);
  const float4* qr = (const float4*)(cb + (size_t)k * DD);
  float4* orow = (float4*)(out_q + (size_t)row * DD);

  float4 xv = xr[t];
  float4 qv = qr[t];
  float dx = qv.x - xv.x, dy = qv.y - xv.y, dz = qv.z - xv.z, dw = qv.w - xv.w;
  float4 o;
  o.x = xv.x + dx; o.y = xv.y + dy; o.z = xv.z + dz; o.w = xv.w + dw;
  orow[t] = o;

  float s0 = dx * dx, s1 = dy * dy, s2 = dz * dz, s3 = dw * dw;
  double part = (double)s0 + (double)s1 + (double)s2 + (double)s3;
  for (int off = 32; off > 0; off >>= 1) part += __shfl_down(part, off, 64);
  __shared__ double red[2];
  const int lane = t & 63, wv = t >> 6;
  if (lane == 0) red[wv] = part;
  __syncthreads();
  if (t == 0) {
    partials[row] = red[0] + red[1];
    out_idx_f[row] = (float)k;
  }
}

// ---------------- reduce partials -> vq_loss
__global__ __launch_bounds__(256) void finalize_kernel(
    const double* __restrict__ partials, float* __restrict__ out_loss) {
  __shared__ double red[256];
  double s = 0.0;
  for (int i = threadIdx.x; i < NROWS; i += 256) s += partials[i];
  red[threadIdx.x] = s;
  __syncthreads();
  for (int st = 128; st > 0; st >>= 1) {
    if (threadIdx.x < st) red[threadIdx.x] += red[threadIdx.x + st];
    __syncthreads();
  }
  if (threadIdx.x == 0) {
    double mean = red[0] / ((double)NROWS * (double)DD);
    float cl = (float)mean;
    out_loss[0] = cl + 0.25f * cl;
  }
}

extern "C" void kernel_launch(void* const* d_in, const int* in_sizes, int n_in,
                              void* d_out, int out_size, void* d_ws,
                              size_t ws_size, hipStream_t stream) {
  const float* x = (const float*)d_in[0];
  const float* cb = (const float*)d_in[1];
  float* out = (float*)d_out;

  // ws: partials | idxbuf | csq | xsq | cnt | list  (~4.5 MB)
  char* ws = (char*)d_ws;
  double* partials = (double*)ws;                          // 262144 B
  int* idxbuf = (int*)(ws + 262144);                       // 131072 B
  float* csq = (float*)(ws + 262144 + 131072);             //  32768 B
  float* xsq = (float*)(ws + 262144 + 131072 + 32768);     // 131072 B
  int* cnt = (int*)(ws + 262144 + 131072 + 32768 + 131072);           // 131072 B
  int* list = (int*)(ws + 262144 + 131072 + 32768 + 131072 + 131072); // 3.1 MB

  // bf16 copies live in d_out scratch (overwritten by epilogue later):
  // cbbf 8.4 MB, xbf 33.5 MB -> 42 MB of the 67 MB output buffer.
  bf16_t* cbbf = (bf16_t*)d_out;
  bf16_t* xbf = cbbf + (size_t)KCODES * DD;

  sumsq_kernel<<<KCODES / 4, 256, 0, stream>>>(cb, csq, KCODES);
  sumsq_kernel<<<NROWS / 4, 256, 0, stream>>>(x, xsq, NROWS);
  cvt_kernel<<<(KCODES * DD / 4) / 256, 256, 0, stream>>>(cb, cbbf);
  cvt_kernel<<<(NROWS * DD / 4) / 256, 256, 0, stream>>>(x, xbf);
  coarse_kernel<<<NROWS / 128, 256, 0, stream>>>(xbf, cbbf, csq, cnt, list);
  rescore_kernel<<<NROWS / 4, 256, 0, stream>>>(x, cb, xsq, csq, list, cnt, idxbuf);
  epilogue_kernel<<<NROWS, 128, 0, stream>>>(x, cb, idxbuf, out,
                                             out + 16777216 + 1, partials);
  finalize_kernel<<<1, 256, 0, stream>>>(partials, out + 16777216);
}

// Round 8
// 1296.333 us; speedup vs baseline: 58.4733x; 1.9956x over previous
//
#include <hip/hip_runtime.h>

// VQ forward on MI355X — round 8: occupancy-shaped bf16 MFMA screen.
// x: [32768,512] fp32, codebook: [8192,512] fp32.
// d_out (fp32): [16.7M) quantized_st | [1] vq_loss | [32768] idx-as-float
//
// R7 post-mortem: screen worked (rescore fell out of top-5) but coarse ran at
// 5.8% of MFMA ceiling: 256 blocks = 1 block/CU = 1 wave/SIMD -> every
// barrier/vmcnt/lgkm stall fully exposed (Occupancy 10.4%). R5 at 8 waves/CU
// hit 28.6% with 3x the MFMAs. R8 reshapes for 2 blocks/CU:
//  - wave tile 64x128 (acc[4][8]=128 VGPRs, ~230 total -> 2 waves/SIMD)
//  - block 128 rows x 4096 codes; grid (256,2) = 512 blocks = 8 waves/CU
//  - LDS 37.5 KB (As 8K + Bs 16K + best/cnt/list 13.5K) -> 2 blocks/CU fits
//  - staging/prefetch/screen logic identical in structure to R7 (validated);
//    rescore = R1's bit-exact fp32 chain (accepted absmax 0 since R1).

#define NROWS 32768
#define KCODES 8192
#define DD 512
#define CAP 24
#define MARGIN 2.5e-4f

typedef __bf16 bf16_t;
typedef __bf16 bf16x4 __attribute__((ext_vector_type(4)));
typedef __bf16 bf16x8 __attribute__((ext_vector_type(8)));
typedef float f32x4 __attribute__((ext_vector_type(4)));

// LDS layout for a [rows][32k] bf16 tile: 16B chunk (row, slot s in 0..3) at
// row*32 + ((s ^ ((row>>1)&3))<<3) bf16. Conflict-free at the b128 8-phase floor.
__device__ __forceinline__ int lofs(int row, int s) {
  return row * 32 + (((s ^ ((row >> 1) & 3))) << 3);
}

// ---------------- sum of fp32 squares per row (fp64 accumulate, round to fp32)
__global__ __launch_bounds__(256) void sumsq_kernel(const float* __restrict__ in,
                                                    float* __restrict__ out,
                                                    int nrows) {
  const int wave = threadIdx.x >> 6;
  const int lane = threadIdx.x & 63;
  const int row = blockIdx.x * 4 + wave;
  if (row >= nrows) return;
  const float* p = in + (size_t)row * DD;
  double s = 0.0;
#pragma unroll
  for (int j = 0; j < DD / 64; ++j) {
    float v = p[j * 64 + lane];
    float sq = v * v;
    s += (double)sq;
  }
  for (int off = 32; off > 0; off >>= 1) s += __shfl_down(s, off, 64);
  if (lane == 0) out[row] = (float)s;
}

// ---------------- fp32 -> bf16 (RNE) bulk convert
__global__ __launch_bounds__(256) void cvt_kernel(const float* __restrict__ in,
                                                  bf16_t* __restrict__ outb) {
  const int t = blockIdx.x * 256 + threadIdx.x;
  float4 v = *(const float4*)(in + (size_t)t * 4);
  bf16x4 o = {(bf16_t)v.x, (bf16_t)v.y, (bf16_t)v.z, (bf16_t)v.w};
  *(bf16x4*)(outb + (size_t)t * 4) = o;
}

// ---------------- coarse: bf16 MFMA GEMM (16x16x32) + prefix-min margin screen
__global__ __launch_bounds__(256, 2) void coarse_kernel(
    const bf16_t* __restrict__ xbf, const bf16_t* __restrict__ cbbf,
    const float* __restrict__ csq, int* __restrict__ cnt_g,
    int* __restrict__ list_g) {
  __shared__ bf16_t As[128 * 32];               //  8 KB
  __shared__ bf16_t Bs[256 * 32];               // 16 KB
  __shared__ unsigned long long best[128];      // packed (dist_bits<<32)|code
  __shared__ int cnt_l[128];
  __shared__ int list_l[128 * CAP];             // 12 KB

  const int tid = threadIdx.x;
  const int w = tid >> 6;
  const int lane = tid & 63;
  const int q = lane >> 4;           // quad: k-group q*8..q*8+7, C rows q*4+reg
  const int l15 = lane & 15;
  const int rOff = (w & 1) * 64;     // wave rows rOff..rOff+63
  const int cOff = (w >> 1) * 128;   // wave cols cOff..cOff+127
  const int row0 = blockIdx.x * 128;
  const int cbase = blockIdx.y * (KCODES / 2);

  for (int i = tid; i < 128; i += 256) { best[i] = ~0ULL; cnt_l[i] = 0; }

  // A staging: thread -> row ar, slots as0, as0+1 (16 contiguous k per round)
  const int ar = tid & 127;
  const int as0 = (tid >> 7) * 2;
  const int aofs0 = lofs(ar, as0);
  const int aofs1 = lofs(ar, as0 + 1);
  const bf16_t* xrow = xbf + (size_t)(row0 + ar) * DD + as0 * 8;

  // B staging: 1024 chunks (256 codes x 4 slots) / 256 thr = 4 per thread
  int bofs[4];
  const bf16_t* cbp[4];
#pragma unroll
  for (int j = 0; j < 4; ++j) {
    const int flat = j * 256 + tid;        // 0..1023
    const int bcode = flat >> 2;           // 0..255 — full 256-code tile
    const int bs = flat & 3;
    bofs[j] = lofs(bcode, bs);
    cbp[j] = cbbf + (size_t)(cbase + bcode) * DD + bs * 8;
  }

  // fragment read offsets
  int afofs[4], bfofs[8];
#pragma unroll
  for (int rt = 0; rt < 4; ++rt) afofs[rt] = lofs(rOff + rt * 16 + l15, q);
#pragma unroll
  for (int ct = 0; ct < 8; ++ct) bfofs[ct] = lofs(cOff + ct * 16 + l15, q);

  // prime prefetch for (ci=0, kc=0)
  bf16x8 pa0 = *(const bf16x8*)(xrow);
  bf16x8 pa1 = *(const bf16x8*)(xrow + 8);
  bf16x8 pb[4];
#pragma unroll
  for (int j = 0; j < 4; ++j) pb[j] = *(const bf16x8*)(cbp[j]);

  __syncthreads();   // best/cnt init visible

#pragma unroll 1
  for (int ci = 0; ci < (KCODES / 2) / 256; ++ci) {
    const int c0 = cbase + ci * 256;
    f32x4 acc[4][8];
#pragma unroll
    for (int rt = 0; rt < 4; ++rt)
#pragma unroll
      for (int ct = 0; ct < 8; ++ct) {
        f32x4 z = {0.f, 0.f, 0.f, 0.f};
        acc[rt][ct] = z;
      }

#pragma unroll 1
    for (int kc = 0; kc < DD / 32; ++kc) {
      // store prefetched round to LDS
      *(bf16x8*)&As[aofs0] = pa0;
      *(bf16x8*)&As[aofs1] = pa1;
#pragma unroll
      for (int j = 0; j < 4; ++j) *(bf16x8*)&Bs[bofs[j]] = pb[j];
      __syncthreads();

      // prefetch next round (next kc, or next ci's kc=0)
      {
        int nci = ci, nkc = kc + 1;
        if (nkc == DD / 32) { nkc = 0; ++nci; }
        if (nci < (KCODES / 2) / 256) {
          const int nkb = nkc * 32;
          const size_t ncoff = (size_t)(nci * 256) * DD + nkb;
          pa0 = *(const bf16x8*)(xrow + nkb);
          pa1 = *(const bf16x8*)(xrow + nkb + 8);
#pragma unroll
          for (int j = 0; j < 4; ++j) pb[j] = *(const bf16x8*)(cbp[j] + ncoff);
        }
      }

      // fragments + 32 MFMAs (16x16x32, one K=32 step per round)
      bf16x8 af[4], bfr[8];
#pragma unroll
      for (int rt = 0; rt < 4; ++rt) af[rt] = *(const bf16x8*)&As[afofs[rt]];
#pragma unroll
      for (int ct = 0; ct < 8; ++ct) bfr[ct] = *(const bf16x8*)&Bs[bfofs[ct]];
#pragma unroll
      for (int rt = 0; rt < 4; ++rt)
#pragma unroll
        for (int ct = 0; ct < 8; ++ct)
          acc[rt][ct] = __builtin_amdgcn_mfma_f32_16x16x32_bf16(
              af[rt], bfr[ct], acc[rt][ct], 0, 0, 0);
      __syncthreads();
    }

    // ---- screen this 256-code tile. d' = 1 + csq - 2*dot (>0, bit-orderable)
    float cs1[8];
#pragma unroll
    for (int ct = 0; ct < 8; ++ct)
      cs1[ct] = 1.0f + csq[c0 + (cOff - cbase * 0) + ct * 16 + l15 - cbase + cbase];  // simplified below
    // (cols are c0 + cOff%?; recompute cleanly:)
#pragma unroll
    for (int ct = 0; ct < 8; ++ct)
      cs1[ct] = 1.0f + csq[c0 + cOff + ct * 16 + l15];

    // min pass (C/D layout m89: col=lane&15, row=q*4+reg)
#pragma unroll
    for (int rt = 0; rt < 4; ++rt) {
#pragma unroll
      for (int reg = 0; reg < 4; ++reg) {
        unsigned long long pk = ~0ULL;
#pragma unroll
        for (int ct = 0; ct < 8; ++ct) {
          float d = fmaf(-2.0f, acc[rt][ct][reg], cs1[ct]);
          unsigned long long p =
              ((unsigned long long)__float_as_uint(d) << 32) |
              (unsigned)(c0 + cOff + ct * 16 + l15);
          if (p < pk) pk = p;
        }
#pragma unroll
        for (int m = 1; m <= 8; m <<= 1) {
          unsigned long long o = __shfl_xor(pk, m, 64);
          if (o < pk) pk = o;
        }
        if (l15 == 0) atomicMin(&best[rOff + rt * 16 + q * 4 + reg], pk);
      }
    }
    __syncthreads();

    // append pass vs prefix-min threshold
#pragma unroll
    for (int rt = 0; rt < 4; ++rt) {
#pragma unroll
      for (int reg = 0; reg < 4; ++reg) {
        const int rloc = rOff + rt * 16 + q * 4 + reg;
        const float thr = __uint_as_float((unsigned)(best[rloc] >> 32)) + MARGIN;
#pragma unroll
        for (int ct = 0; ct < 8; ++ct) {
          float d = fmaf(-2.0f, acc[rt][ct][reg], cs1[ct]);
          if (d <= thr) {
            int pos = atomicAdd(&cnt_l[rloc], 1);
            if (pos < CAP)
              list_l[rloc * CAP + pos] = c0 + cOff + ct * 16 + l15;
          }
        }
      }
    }
    __syncthreads();
  }

  // per-half outputs: cnt/list indexed by (row, half)
  const int half = blockIdx.y;
  for (int i = tid; i < 128; i += 256) cnt_g[(row0 + i) * 2 + half] = cnt_l[i];
  for (int i = tid; i < 128 * CAP; i += 256) {
    const int r = i / CAP, p = i % CAP;
    list_g[((size_t)(row0 + r) * 2 + half) * CAP + p] = list_l[i];
  }
}

// ---------------- phase 2: exact rescore of candidates (R1's bit-exact chain)
__global__ __launch_bounds__(256) void rescore_kernel(
    const float* __restrict__ x, const float* __restrict__ cb,
    const float* __restrict__ xsq, const float* __restrict__ csq,
    const int* __restrict__ list, const int* __restrict__ cnt,
    int* __restrict__ idxbuf) {
  const int row = blockIdx.x * 4 + (threadIdx.x >> 6);
  const int lane = threadIdx.x & 63;
  const int n0 = cnt[row * 2];
  const int n1 = cnt[row * 2 + 1];
  const float xs = xsq[row];
  const float4* xr4 = (const float4*)(x + (size_t)row * DD);
  unsigned long long bestv = ~0ULL;

  if (n0 >= 1 && n0 <= CAP && n1 >= 0 && n1 <= CAP && (n0 + n1) <= 56) {
    int myidx = -1;
    if (lane < n0) myidx = list[((size_t)row * 2) * CAP + lane];
    else if (lane - n0 < n1) myidx = list[((size_t)row * 2 + 1) * CAP + (lane - n0)];
    if (myidx >= 0) {
      const float4* cr4 = (const float4*)(cb + (size_t)myidx * DD);
      float acc = 0.0f;
      for (int k4 = 0; k4 < DD / 4; ++k4) {     // sequential ascending k: R1 order
        float4 xv = xr4[k4];
        float4 cv = cr4[k4];
        acc = fmaf(xv.x, cv.x, acc);
        acc = fmaf(xv.y, cv.y, acc);
        acc = fmaf(xv.z, cv.z, acc);
        acc = fmaf(xv.w, cv.w, acc);
      }
      float t = xs - 2.0f * acc;
      float d = t + csq[myidx];
      bestv = ((unsigned long long)__float_as_uint(d) << 32) | (unsigned)myidx;
    }
  } else {
    // safety fallback: full exact scan
    for (int idx = lane; idx < KCODES; idx += 64) {
      const float4* cr4 = (const float4*)(cb + (size_t)idx * DD);
      float acc = 0.0f;
      for (int k4 = 0; k4 < DD / 4; ++k4) {
        float4 xv = xr4[k4];
        float4 cv = cr4[k4];
        acc = fmaf(xv.x, cv.x, acc);
        acc = fmaf(xv.y, cv.y, acc);
        acc = fmaf(xv.z, cv.z, acc);
        acc = fmaf(xv.w, cv.w, acc);
      }
      float t = xs - 2.0f * acc;
      float d = t + csq[idx];
      unsigned long long pk =
          ((unsigned long long)__float_as_uint(d) << 32) | (unsigned)idx;
      if (pk < bestv) bestv = pk;
    }
  }
#pragma unroll
  for (int s = 1; s <= 32; s <<= 1) {
    unsigned long long o = __shfl_xor(bestv, s, 64);
    if (o < bestv) bestv = o;
  }
  if (lane == 0) idxbuf[row] = (int)(bestv & 0xffffffffu);
}

// ---------------- gather + straight-through + loss partial + idx-as-float
__global__ __launch_bounds__(128) void epilogue_kernel(
    const float* __restrict__ x, const float* __restrict__ cb,
    const int* __restrict__ idxbuf, float* __restrict__ out_q,
    float* __restrict__ out_idx_f, double* __restrict__ partials) {
  const int row = blockIdx.x;
  const int t = threadIdx.x;
  const int k = idxbuf[row];

  const float4* xr = (const float4*)(x + (size_t)row * DD);
  const float4* qr = (const float4*)(cb + (size_t)k * DD);
  float4* orow = (float4*)(out_q + (size_t)row * DD);

  float4 xv = xr[t];
  float4 qv = qr[t];
  float dx = qv.x - xv.x, dy = qv.y - xv.y, dz = qv.z - xv.z, dw = qv.w - xv.w;
  float4 o;
  o.x = xv.x + dx; o.y = xv.y + dy; o.z = xv.z + dz; o.w = xv.w + dw;
  orow[t] = o;

  float s0 = dx * dx, s1 = dy * dy, s2 = dz * dz, s3 = dw * dw;
  double part = (double)s0 + (double)s1 + (double)s2 + (double)s3;
  for (int off = 32; off > 0; off >>= 1) part += __shfl_down(part, off, 64);
  __shared__ double red[2];
  const int lane = t & 63, wv = t >> 6;
  if (lane == 0) red[wv] = part;
  __syncthreads();
  if (t == 0) {
    partials[row] = red[0] + red[1];
    out_idx_f[row] = (float)k;
  }
}

// ---------------- reduce partials -> vq_loss
__global__ __launch_bounds__(256) void finalize_kernel(
    const double* __restrict__ partials, float* __restrict__ out_loss) {
  __shared__ double red[256];
  double s = 0.0;
  for (int i = threadIdx.x; i < NROWS; i += 256) s += partials[i];
  red[threadIdx.x] = s;
  __syncthreads();
  for (int st = 128; st > 0; st >>= 1) {
    if (threadIdx.x < st) red[threadIdx.x] += red[threadIdx.x + st];
    __syncthreads();
  }
  if (threadIdx.x == 0) {
    double mean = red[0] / ((double)NROWS * (double)DD);
    float cl = (float)mean;
    out_loss[0] = cl + 0.25f * cl;
  }
}

extern "C" void kernel_launch(void* const* d_in, const int* in_sizes, int n_in,
                              void* d_out, int out_size, void* d_ws,
                              size_t ws_size, hipStream_t stream) {
  const float* x = (const float*)d_in[0];
  const float* cb = (const float*)d_in[1];
  float* out = (float*)d_out;

  // ws: partials | idxbuf | csq | xsq | cnt(2/row) | list(2 halves/row)
  char* ws = (char*)d_ws;
  double* partials = (double*)ws;                          // 262144 B
  int* idxbuf = (int*)(ws + 262144);                       // 131072 B
  float* csq = (float*)(ws + 262144 + 131072);             //  32768 B
  float* xsq = (float*)(ws + 262144 + 131072 + 32768);     // 131072 B
  int* cnt = (int*)(ws + 262144 + 131072 + 32768 + 131072);           // 262144 B
  int* list = (int*)(ws + 262144 + 131072 + 32768 + 131072 + 262144); // 6.3 MB

  // bf16 copies live in d_out scratch (overwritten by epilogue later)
  bf16_t* cbbf = (bf16_t*)d_out;
  bf16_t* xbf = cbbf + (size_t)KCODES * DD;

  sumsq_kernel<<<KCODES / 4, 256, 0, stream>>>(cb, csq, KCODES);
  sumsq_kernel<<<NROWS / 4, 256, 0, stream>>>(x, xsq, NROWS);
  cvt_kernel<<<(KCODES * DD / 4) / 256, 256, 0, stream>>>(cb, cbbf);
  cvt_kernel<<<(NROWS * DD / 4) / 256, 256, 0, stream>>>(x, xbf);
  dim3 grid(NROWS / 128, 2);
  coarse_kernel<<<grid, 256, 0, stream>>>(xbf, cbbf, csq, cnt, list);
  rescore_kernel<<<NROWS / 4, 256, 0, stream>>>(x, cb, xsq, csq, list, cnt, idxbuf);
  epilogue_kernel<<<NROWS, 128, 0, stream>>>(x, cb, idxbuf, out,
                                             out + 16777216 + 1, partials);
  finalize_kernel<<<1, 256, 0, stream>>>(partials, out + 16777216);
}

// Round 9
// 1057.120 us; speedup vs baseline: 71.7052x; 1.2263x over previous
//
#include <hip/hip_runtime.h>

// VQ forward on MI355X — round 9: global_load_lds staging (m97 pattern).
// x: [32768,512] fp32, codebook: [8192,512] fp32.
// d_out (fp32): [16.7M) quantized_st | [1] vq_loss | [32768] idx-as-float
//
// R8 post-mortem: VGPR_Count=128 + WRITE_SIZE=465MB -> acc[4][8] took 128 of
// the 256-reg unified budget (2 waves/SIMD) and the staging/prefetch regs
// (~60) spilled to scratch every ci iteration. R9 removes the staging VGPRs
// entirely: __builtin_amdgcn_global_load_lds width=16 DMAs A/B straight to
// LDS (6 calls/wave/round). Lane mapping chosen so the wave-uniform-base +
// lane*16 scatter lands exactly in the swizzled lofs layout (lane l -> row
// base+(l>>2), pos l&3 holds global slot (l&3)^((row>>1)&3)) -> fragment
// reads identical to R8. Budget: 128 AGPR + ~100 VGPR < 256 -> no spill,
// 2 blocks/CU, 8 waves/CU. Screen + exact rescore unchanged (absmax 0
// since R1).

#define NROWS 32768
#define KCODES 8192
#define DD 512
#define CAP 24
#define MARGIN 2.5e-4f

typedef __bf16 bf16_t;
typedef __bf16 bf16x4 __attribute__((ext_vector_type(4)));
typedef __bf16 bf16x8 __attribute__((ext_vector_type(8)));
typedef float f32x4 __attribute__((ext_vector_type(4)));

// LDS layout: 16B chunk (row, slot s in 0..3) at byte row*64 + (s^((row>>1)&3))*16.
__device__ __forceinline__ int lofs(int row, int s) {
  return row * 32 + (((s ^ ((row >> 1) & 3))) << 3);   // bf16-element offset
}

__device__ __forceinline__ void gld16(const bf16_t* g, bf16_t* l) {
  __builtin_amdgcn_global_load_lds(
      (const __attribute__((address_space(1))) void*)g,
      (__attribute__((address_space(3))) void*)l, 16, 0, 0);
}

// ---------------- sum of fp32 squares per row (fp64 accumulate, round to fp32)
__global__ __launch_bounds__(256) void sumsq_kernel(const float* __restrict__ in,
                                                    float* __restrict__ out,
                                                    int nrows) {
  const int wave = threadIdx.x >> 6;
  const int lane = threadIdx.x & 63;
  const int row = blockIdx.x * 4 + wave;
  if (row >= nrows) return;
  const float* p = in + (size_t)row * DD;
  double s = 0.0;
#pragma unroll
  for (int j = 0; j < DD / 64; ++j) {
    float v = p[j * 64 + lane];
    float sq = v * v;
    s += (double)sq;
  }
  for (int off = 32; off > 0; off >>= 1) s += __shfl_down(s, off, 64);
  if (lane == 0) out[row] = (float)s;
}

// ---------------- fp32 -> bf16 (RNE) bulk convert
__global__ __launch_bounds__(256) void cvt_kernel(const float* __restrict__ in,
                                                  bf16_t* __restrict__ outb) {
  const int t = blockIdx.x * 256 + threadIdx.x;
  float4 v = *(const float4*)(in + (size_t)t * 4);
  bf16x4 o = {(bf16_t)v.x, (bf16_t)v.y, (bf16_t)v.z, (bf16_t)v.w};
  *(bf16x4*)(outb + (size_t)t * 4) = o;
}

// ---------------- coarse: bf16 MFMA GEMM (16x16x32) + prefix-min margin screen
__global__ __launch_bounds__(256, 2) void coarse_kernel(
    const bf16_t* __restrict__ xbf, const bf16_t* __restrict__ cbbf,
    const float* __restrict__ csq, int* __restrict__ cnt_g,
    int* __restrict__ list_g) {
  __shared__ bf16_t As[128 * 32];               //  8 KB
  __shared__ bf16_t Bs[256 * 32];               // 16 KB
  __shared__ unsigned long long best[128];      // packed (dist_bits<<32)|code
  __shared__ int cnt_l[128];
  __shared__ int list_l[128 * CAP];             // 12 KB

  const int tid = threadIdx.x;
  const int w = tid >> 6;
  const int lane = tid & 63;
  const int q = lane >> 4;           // quad: k-group q*8..q*8+7, C rows q*4+reg
  const int l15 = lane & 15;
  const int rOff = (w & 1) * 64;     // wave rows rOff..rOff+63
  const int cOff = (w >> 1) * 128;   // wave cols cOff..cOff+127
  const int row0 = blockIdx.x * 128;
  const int cbase = blockIdx.y * (KCODES / 2);

  for (int i = tid; i < 128; i += 256) { best[i] = ~0ULL; cnt_l[i] = 0; }

  // ---- DMA staging assignments (lane-fixed; only kb / ci vary per round) ----
  // Each gld16 call: 64 lanes x 16B = 16 rows. lane l -> row rb+(l>>2),
  // LDS pos p=l&3, global slot sg = p ^ ((row>>1)&3). LDS dest offset
  // row*64 + p*16 bytes = base + l*16: contiguous in lane order (HW scatter).
  const int sub = lane >> 2;                 // 0..15 row-within-call
  const int pos = lane & 3;
  // A: wave w covers rows w*32 .. w*32+31 (2 calls of 16 rows)
  int arowc[2];
  const bf16_t *agp[2];                      // global ptr at kb=0
  bf16_t *alp[2];                            // LDS dest (this lane's slot)
#pragma unroll
  for (int a = 0; a < 2; ++a) {
    const int row = w * 32 + a * 16 + sub;
    const int sg = pos ^ ((row >> 1) & 3);
    arowc[a] = row;
    agp[a] = xbf + (size_t)(row0 + row) * DD + sg * 8;
    alp[a] = As + row * 32 + pos * 8;
  }
  // B: wave w covers codes w*64 .. w*64+63 (4 calls of 16 codes)
  const bf16_t *bgp[4];
  bf16_t *blp[4];
#pragma unroll
  for (int b = 0; b < 4; ++b) {
    const int row = w * 64 + b * 16 + sub;
    const int sg = pos ^ ((row >> 1) & 3);
    bgp[b] = cbbf + (size_t)(cbase + row) * DD + sg * 8;
    blp[b] = Bs + row * 32 + pos * 8;
  }

  // fragment read offsets
  int afofs[4], bfofs[8];
#pragma unroll
  for (int rt = 0; rt < 4; ++rt) afofs[rt] = lofs(rOff + rt * 16 + l15, q);
#pragma unroll
  for (int ct = 0; ct < 8; ++ct) bfofs[ct] = lofs(cOff + ct * 16 + l15, q);

  __syncthreads();   // best/cnt init visible

#pragma unroll 1
  for (int ci = 0; ci < (KCODES / 2) / 256; ++ci) {
    const int c0 = cbase + ci * 256;
    const size_t coff = (size_t)(ci * 256) * DD;
    f32x4 acc[4][8];
#pragma unroll
    for (int rt = 0; rt < 4; ++rt)
#pragma unroll
      for (int ct = 0; ct < 8; ++ct) {
        f32x4 z = {0.f, 0.f, 0.f, 0.f};
        acc[rt][ct] = z;
      }

#pragma unroll 1
    for (int kc = 0; kc < DD / 32; ++kc) {
      const int kb = kc * 32;
      __syncthreads();               // previous round's readers done
      // async DMA this round's tiles into LDS (no VGPR round-trip)
      gld16(agp[0] + kb, alp[0]);
      gld16(agp[1] + kb, alp[1]);
#pragma unroll
      for (int b = 0; b < 4; ++b) gld16(bgp[b] + coff + kb, blp[b]);
      __syncthreads();               // vmcnt(0) drain -> tiles ready

      // fragments + 32 MFMAs (16x16x32, one K=32 step per round)
      bf16x8 af[4], bfr[8];
#pragma unroll
      for (int rt = 0; rt < 4; ++rt) af[rt] = *(const bf16x8*)&As[afofs[rt]];
#pragma unroll
      for (int ct = 0; ct < 8; ++ct) bfr[ct] = *(const bf16x8*)&Bs[bfofs[ct]];
#pragma unroll
      for (int rt = 0; rt < 4; ++rt)
#pragma unroll
        for (int ct = 0; ct < 8; ++ct)
          acc[rt][ct] = __builtin_amdgcn_mfma_f32_16x16x32_bf16(
              af[rt], bfr[ct], acc[rt][ct], 0, 0, 0);
    }

    // ---- screen this 256-code tile. d' = 1 + csq - 2*dot (>0, bit-orderable)
    float cs1[8];
#pragma unroll
    for (int ct = 0; ct < 8; ++ct)
      cs1[ct] = 1.0f + csq[c0 + cOff + ct * 16 + l15];

    // min pass (C/D layout m89: col=lane&15, row=q*4+reg)
#pragma unroll
    for (int rt = 0; rt < 4; ++rt) {
#pragma unroll
      for (int reg = 0; reg < 4; ++reg) {
        unsigned long long pk = ~0ULL;
#pragma unroll
        for (int ct = 0; ct < 8; ++ct) {
          float d = fmaf(-2.0f, acc[rt][ct][reg], cs1[ct]);
          unsigned long long p =
              ((unsigned long long)__float_as_uint(d) << 32) |
              (unsigned)(c0 + cOff + ct * 16 + l15);
          if (p < pk) pk = p;
        }
#pragma unroll
        for (int m = 1; m <= 8; m <<= 1) {
          unsigned long long o = __shfl_xor(pk, m, 64);
          if (o < pk) pk = o;
        }
        if (l15 == 0) atomicMin(&best[rOff + rt * 16 + q * 4 + reg], pk);
      }
    }
    __syncthreads();

    // append pass vs prefix-min threshold
#pragma unroll
    for (int rt = 0; rt < 4; ++rt) {
#pragma unroll
      for (int reg = 0; reg < 4; ++reg) {
        const int rloc = rOff + rt * 16 + q * 4 + reg;
        const float thr = __uint_as_float((unsigned)(best[rloc] >> 32)) + MARGIN;
#pragma unroll
        for (int ct = 0; ct < 8; ++ct) {
          float d = fmaf(-2.0f, acc[rt][ct][reg], cs1[ct]);
          if (d <= thr) {
            int pos2 = atomicAdd(&cnt_l[rloc], 1);
            if (pos2 < CAP)
              list_l[rloc * CAP + pos2] = c0 + cOff + ct * 16 + l15;
          }
        }
      }
    }
    __syncthreads();
  }

  // per-half outputs: cnt/list indexed by (row, half)
  const int half = blockIdx.y;
  for (int i = tid; i < 128; i += 256) cnt_g[(row0 + i) * 2 + half] = cnt_l[i];
  for (int i = tid; i < 128 * CAP; i += 256) {
    const int r = i / CAP, p = i % CAP;
    list_g[((size_t)(row0 + r) * 2 + half) * CAP + p] = list_l[i];
  }
}

// ---------------- phase 2: exact rescore of candidates (R1's bit-exact chain)
__global__ __launch_bounds__(256) void rescore_kernel(
    const float* __restrict__ x, const float* __restrict__ cb,
    const float* __restrict__ xsq, const float* __restrict__ csq,
    const int* __restrict__ list, const int* __restrict__ cnt,
    int* __restrict__ idxbuf) {
  const int row = blockIdx.x * 4 + (threadIdx.x >> 6);
  const int lane = threadIdx.x & 63;
  const int n0 = cnt[row * 2];
  const int n1 = cnt[row * 2 + 1];
  const float xs = xsq[row];
  const float4* xr4 = (const float4*)(x + (size_t)row * DD);
  unsigned long long bestv = ~0ULL;

  if (n0 >= 1 && n0 <= CAP && n1 >= 0 && n1 <= CAP && (n0 + n1) <= 56) {
    int myidx = -1;
    if (lane < n0) myidx = list[((size_t)row * 2) * CAP + lane];
    else if (lane - n0 < n1) myidx = list[((size_t)row * 2 + 1) * CAP + (lane - n0)];
    if (myidx >= 0) {
      const float4* cr4 = (const float4*)(cb + (size_t)myidx * DD);
      float acc = 0.0f;
      for (int k4 = 0; k4 < DD / 4; ++k4) {     // sequential ascending k: R1 order
        float4 xv = xr4[k4];
        float4 cv = cr4[k4];
        acc = fmaf(xv.x, cv.x, acc);
        acc = fmaf(xv.y, cv.y, acc);
        acc = fmaf(xv.z, cv.z, acc);
        acc = fmaf(xv.w, cv.w, acc);
      }
      float t = xs - 2.0f * acc;
      float d = t + csq[myidx];
      bestv = ((unsigned long long)__float_as_uint(d) << 32) | (unsigned)myidx;
    }
  } else {
    // safety fallback: full exact scan
    for (int idx = lane; idx < KCODES; idx += 64) {
      const float4* cr4 = (const float4*)(cb + (size_t)idx * DD);
      float acc = 0.0f;
      for (int k4 = 0; k4 < DD / 4; ++k4) {
        float4 xv = xr4[k4];
        float4 cv = cr4[k4];
        acc = fmaf(xv.x, cv.x, acc);
        acc = fmaf(xv.y, cv.y, acc);
        acc = fmaf(xv.z, cv.z, acc);
        acc = fmaf(xv.w, cv.w, acc);
      }
      float t = xs - 2.0f * acc;
      float d = t + csq[idx];
      unsigned long long pk =
          ((unsigned long long)__float_as_uint(d) << 32) | (unsigned)idx;
      if (pk < bestv) bestv = pk;
    }
  }
#pragma unroll
  for (int s = 1; s <= 32; s <<= 1) {
    unsigned long long o = __shfl_xor(bestv, s, 64);
    if (o < bestv) bestv = o;
  }
  if (lane == 0) idxbuf[row] = (int)(bestv & 0xffffffffu);
}

// ---------------- gather + straight-through + loss partial + idx-as-float
__global__ __launch_bounds__(128) void epilogue_kernel(
    const float* __restrict__ x, const float* __restrict__ cb,
    const int* __restrict__ idxbuf, float* __restrict__ out_q,
    float* __restrict__ out_idx_f, double* __restrict__ partials) {
  const int row = blockIdx.x;
  const int t = threadIdx.x;
  const int k = idxbuf[row];

  const float4* xr = (const float4*)(x + (size_t)row * DD);
  const float4* qr = (const float4*)(cb + (size_t)k * DD);
  float4* orow = (float4*)(out_q + (size_t)row * DD);

  float4 xv = xr[t];
  float4 qv = qr[t];
  float dx = qv.x - xv.x, dy = qv.y - xv.y, dz = qv.z - xv.z, dw = qv.w - xv.w;
  float4 o;
  o.x = xv.x + dx; o.y = xv.y + dy; o.z = xv.z + dz; o.w = xv.w + dw;
  orow[t] = o;

  float s0 = dx * dx, s1 = dy * dy, s2 = dz * dz, s3 = dw * dw;
  double part = (double)s0 + (double)s1 + (double)s2 + (double)s3;
  for (int off = 32; off > 0; off >>= 1) part += __shfl_down(part, off, 64);
  __shared__ double red[2];
  const int lane = t & 63, wv = t >> 6;
  if (lane == 0) red[wv] = part;
  __syncthreads();
  if (t == 0) {
    partials[row] = red[0] + red[1];
    out_idx_f[row] = (float)k;
  }
}

// ---------------- reduce partials -> vq_loss
__global__ __launch_bounds__(256) void finalize_kernel(
    const double* __restrict__ partials, float* __restrict__ out_loss) {
  __shared__ double red[256];
  double s = 0.0;
  for (int i = threadIdx.x; i < NROWS; i += 256) s += partials[i];
  red[threadIdx.x] = s;
  __syncthreads();
  for (int st = 128; st > 0; st >>= 1) {
    if (threadIdx.x < st) red[threadIdx.x] += red[threadIdx.x + st];
    __syncthreads();
  }
  if (threadIdx.x == 0) {
    double mean = red[0] / ((double)NROWS * (double)DD);
    float cl = (float)mean;
    out_loss[0] = cl + 0.25f * cl;
  }
}

extern "C" void kernel_launch(void* const* d_in, const int* in_sizes, int n_in,
                              void* d_out, int out_size, void* d_ws,
                              size_t ws_size, hipStream_t stream) {
  const float* x = (const float*)d_in[0];
  const float* cb = (const float*)d_in[1];
  float* out = (float*)d_out;

  // ws: partials | idxbuf | csq | xsq | cnt(2/row) | list(2 halves/row)
  char* ws = (char*)d_ws;
  double* partials = (double*)ws;                          // 262144 B
  int* idxbuf = (int*)(ws + 262144);                       // 131072 B
  float* csq = (float*)(ws + 262144 + 131072);             //  32768 B
  float* xsq = (float*)(ws + 262144 + 131072 + 32768);     // 131072 B
  int* cnt = (int*)(ws + 262144 + 131072 + 32768 + 131072);           // 262144 B
  int* list = (int*)(ws + 262144 + 131072 + 32768 + 131072 + 262144); // 6.3 MB

  // bf16 copies live in d_out scratch (overwritten by epilogue later)
  bf16_t* cbbf = (bf16_t*)d_out;
  bf16_t* xbf = cbbf + (size_t)KCODES * DD;

  sumsq_kernel<<<KCODES / 4, 256, 0, stream>>>(cb, csq, KCODES);
  sumsq_kernel<<<NROWS / 4, 256, 0, stream>>>(x, xsq, NROWS);
  cvt_kernel<<<(KCODES * DD / 4) / 256, 256, 0, stream>>>(cb, cbbf);
  cvt_kernel<<<(NROWS * DD / 4) / 256, 256, 0, stream>>>(x, xbf);
  dim3 grid(NROWS / 128, 2);
  coarse_kernel<<<grid, 256, 0, stream>>>(xbf, cbbf, csq, cnt, list);
  rescore_kernel<<<NROWS / 4, 256, 0, stream>>>(x, cb, xsq, csq, list, cnt, idxbuf);
  epilogue_kernel<<<NROWS, 128, 0, stream>>>(x, cb, idxbuf, out,
                                             out + 16777216 + 1, partials);
  finalize_kernel<<<1, 256, 0, stream>>>(partials, out + 16777216);
}